// Round 6
// baseline (227.141 us; speedup 1.0000x reference)
//
#include <hip/hip_runtime.h>
#include <hip/hip_bf16.h>
#include <math.h>

#define B 4096
#define NF 50
#define BN_EPS 1e-3f
#define ROWS 8

typedef float f32x4 __attribute__((ext_vector_type(4)));
typedef __bf16 bf16x8 __attribute__((ext_vector_type(8)));
#define MFMA __builtin_amdgcn_mfma_f32_16x16x32_bf16

__device__ __forceinline__ unsigned short f2b(float x) {
  unsigned u = __float_as_uint(x);
  return (unsigned short)((u + 0x7FFFu + ((u >> 16) & 1u)) >> 16);  // RNE
}
__device__ __forceinline__ unsigned packbf(float a, float b) {
  return ((unsigned)f2b(b) << 16) | (unsigned)f2b(a);
}
__device__ __forceinline__ float bs2f(unsigned short u) {
  return __uint_as_float(((unsigned)u) << 16);
}

// ---- workspace (unsigned short elems), all B-operands n-major/k-contig ----
#define WS_LS  0        // [64][3200]
#define WS_QW  204800   // [64][4096]
#define WS_W0  466944   // [512][192]
#define WS_W1  565248   // [256][512]
#define WS_W2  696320   // [128][256]

// ===========================================================================
// prep: ls/qw bf16 convert (vectorized) + W transposes via LDS 64x64 tiles
__global__ __launch_bounds__(256) void prep(
    const float* __restrict__ ls, const float* __restrict__ qw,
    const float* __restrict__ W0, const float* __restrict__ W1,
    const float* __restrict__ W2, unsigned short* __restrict__ ws)
{
  int bid = blockIdx.x, t = threadIdx.x;
  if (bid < 228) {                // straight converts: ls (100 blocks) + qw (128)
    int o = (bid * 256 + t) * 8;  // ls occupies [0,204800), qw [204800,467..)
    const float* src = (o < 204800) ? (ls + o) : (qw + (o - 204800));
    float4 a = *(const float4*)src, b = *(const float4*)(src + 4);
    int4 v = {(int)packbf(a.x, a.y), (int)packbf(a.z, a.w),
              (int)packbf(b.x, b.y), (int)packbf(b.z, b.w)};
    *(int4*)&ws[o] = v;
    return;
  }
  // W transposes: out[n][k] = W[k][n]
  __shared__ unsigned short sh[64 * 72];
  int id = bid - 228;
  const float* W; int K, Ncols, kt, nt, wofs;
  if (id < 24)      { W = W0; K = 192; Ncols = 512; kt = id >> 3; nt = id & 7;  wofs = WS_W0; }
  else if (id < 56) { int j = id - 24; W = W1; K = 512; Ncols = 256; kt = j >> 2; nt = j & 3; wofs = WS_W1; }
  else              { int j = id - 56; W = W2; K = 256; Ncols = 128; kt = j >> 1; nt = j & 1; wofs = WS_W2; }
  int k0 = kt * 64, n0 = nt * 64;
  {
    int r = t >> 2, cs = (t & 3) * 16;            // load 64k x 64n, coalesced on n
    const float* src = W + (size_t)(k0 + r) * Ncols + n0 + cs;
    float4 a = *(const float4*)src, b = *(const float4*)(src + 4);
    float4 c = *(const float4*)(src + 8), d = *(const float4*)(src + 12);
    unsigned short* dst = &sh[r * 72 + cs];
    *(int4*)dst = int4{(int)packbf(a.x, a.y), (int)packbf(a.z, a.w),
                       (int)packbf(b.x, b.y), (int)packbf(b.z, b.w)};
    *(int4*)(dst + 8) = int4{(int)packbf(c.x, c.y), (int)packbf(c.z, c.w),
                             (int)packbf(d.x, d.y), (int)packbf(d.z, d.w)};
  }
  __syncthreads();
  {
    int nr = t >> 2, ks = (t & 3) * 16;           // store 64n x 64k, coalesced on k
    unsigned short vbuf[16];
#pragma unroll
    for (int j = 0; j < 16; ++j) vbuf[j] = sh[(ks + j) * 72 + nr];
    unsigned short* dst = &ws[wofs + (size_t)(n0 + nr) * K + k0 + ks];
    *(int4*)dst = *(int4*)&vbuf[0];
    *(int4*)(dst + 8) = *(int4*)&vbuf[8];
  }
}

// ===========================================================================
// 512 blocks x 256 threads (4 waves). 8 batch rows/block.
// Wave w owns d/n-tile [16w,16w+16), full K. A-frag rows clamp &7 (dup rows).
__global__ __launch_bounds__(256, 4) void pnn_main(
    const float* __restrict__ fv, const int* __restrict__ idx,
    const float* __restrict__ emb, const float* __restrict__ theta,
    const unsigned short* __restrict__ ws,
    const float* __restrict__ b0p, const float* __restrict__ g0p,
    const float* __restrict__ be0p, const float* __restrict__ m0p,
    const float* __restrict__ v0p,
    const float* __restrict__ b1p, const float* __restrict__ g1p,
    const float* __restrict__ be1p, const float* __restrict__ m1p,
    const float* __restrict__ v1p,
    const float* __restrict__ b2p, const float* __restrict__ g2p,
    const float* __restrict__ be2p, const float* __restrict__ m2p,
    const float* __restrict__ v2p,
    const float* __restrict__ Wout, const float* __restrict__ boutp,
    float* __restrict__ out)
{
  __shared__ int   idx_s[ROWS * NF];
  __shared__ float fv_s[ROWS * NF];
  __shared__ float th2_s[64 * NF];
  __shared__ float s_s[ROWS * 64];
  __shared__ float sq_s[ROWS * 64];
  __shared__ unsigned short fbuf[2][ROWS * 264];   // dbuf A chunks [8][256+8]
  __shared__ unsigned short x_s[ROWS * 200];       // [8][192+8]
  __shared__ unsigned short h0_s[ROWS * 520];      // [8][512+8]
  __shared__ unsigned short h1_s[ROWS * 264];      // [8][256+8]
  __shared__ unsigned short h2_s[ROWS * 136];      // [8][128+8]

  const unsigned short* lsb = ws + WS_LS;
  const unsigned short* qwb = ws + WS_QW;
  const unsigned short* w0t = ws + WS_W0;
  const unsigned short* w1t = ws + WS_W1;
  const unsigned short* w2t = ws + WS_W2;

  const int t    = threadIdx.x;
  const int w    = t >> 6;          // wave 0..3
  const int l    = t & 63;
  const int m16  = l & 15;
  const int qoff = (l >> 4) * 8;    // A/B frag k-offset
  const int d0   = w * 16;          // this wave's n/d tile
  const int b0   = blockIdx.x * ROWS;
  const int bq   = t >> 5;          // staging row 0..7
  const int i2   = (t & 31) * 2;    // staging col pair
  const int arow = (m16 & 7) * 264 + qoff;

  // ---------------- phase 0 ----------------
  for (int i = t; i < ROWS * NF; i += 256) {
    idx_s[i] = idx[b0 * NF + i];
    fv_s[i]  = fv[b0 * NF + i];
  }
  for (int i = t; i < 64 * NF; i += 256) { float v = theta[i]; th2_s[i] = v * v; }
  __syncthreads();

  // ---------------- phase 1: l_z (K=3200), s, sq ----------------
  float s0 = 0.f, s1 = 0.f;
  f32x4 az0 = {0.f, 0.f, 0.f, 0.f}, az1 = {0.f, 0.f, 0.f, 0.f};

  for (int c = 0; c < 13; ++c) {
    unsigned short* fb = fbuf[c & 1];
    int nfld = (c < 12) ? 4 : 2;
#pragma unroll
    for (int h = 0; h < 4; ++h) {
      if (h < nfld) {
        int n = 4 * c + h;
        int iv = idx_s[bq * NF + n];
        float fvv = fv_s[bq * NF + n];
        float2 e = *(const float2*)(emb + (size_t)iv * 64 + i2);
        float p0 = fvv * e.x, p1 = fvv * e.y;
        *(unsigned*)&fb[bq * 264 + h * 64 + i2] = packbf(p0, p1);
        s0 += p0; s1 += p1;
        float q = p0 * p0 + p1 * p1;
        q += __shfl_xor(q, 16); q += __shfl_xor(q, 8); q += __shfl_xor(q, 4);
        q += __shfl_xor(q, 2);  q += __shfl_xor(q, 1);
        if ((t & 31) == 0) sq_s[bq * 64 + n] = q;
      }
    }
    __syncthreads();
    const unsigned short* lp = lsb + (size_t)(d0 + m16) * 3200 + c * 256 + qoff;
    int nfr = nfld * 2;
#pragma unroll 4
    for (int kc = 0; kc < nfr; ++kc) {
      bf16x8 av = *(const bf16x8*)&fb[arow + kc * 32];
      bf16x8 bv = *(const bf16x8*)(lp + kc * 32);
      if (kc & 1) az1 = MFMA(av, bv, az1, 0, 0, 0);
      else        az0 = MFMA(av, bv, az0, 0, 0, 0);
    }
  }
  { float2 sv; sv.x = s0; sv.y = s1; *(float2*)&s_s[bq * 64 + i2] = sv; }
  // l_z -> x[:,0:64)
  if (l < 32) {
#pragma unroll
    for (int r = 0; r < 4; ++r) {
      float v = az0[r] + az1[r];
      x_s[((l >> 4) * 4 + r) * 200 + d0 + m16] = f2b(v);
    }
  }
  // l_p_in -> x[:,64:128)  (needs sq_s complete: written before last sync? No —
  // chunk-12 sq writes precede the chunk-12 sync inside the loop. Safe.)
  {
    int d = t & 63, g = t >> 6;
    float a0 = 0.f, a1 = 0.f;
    for (int n = 0; n < NF; ++n) {
      float th2 = th2_s[d * NF + n];
      a0 += sq_s[g * 64 + n] * th2;
      a1 += sq_s[(g + 4) * 64 + n] * th2;
    }
    x_s[g * 200 + 64 + d]       = f2b(a0);
    x_s[(g + 4) * 200 + 64 + d] = f2b(a1);
  }
  __syncthreads();   // s_s/x_s visible to all

  // ---------------- phase 2: l_p_out (K=4096, k=m*64+n) ----------------
  {
    f32x4 ap0 = {0.f, 0.f, 0.f, 0.f}, ap1 = {0.f, 0.f, 0.f, 0.f};
    for (int c = 0; c < 16; ++c) {
      unsigned short* fb = fbuf[c & 1];
#pragma unroll
      for (int h = 0; h < 4; ++h) {
        int mq = 4 * c + h;
        float pm = s_s[bq * 64 + mq];
        float p0 = pm * s_s[bq * 64 + i2];
        float p1 = pm * s_s[bq * 64 + i2 + 1];
        *(unsigned*)&fb[bq * 264 + h * 64 + i2] = packbf(p0, p1);
      }
      __syncthreads();
      const unsigned short* qp = qwb + (size_t)(d0 + m16) * 4096 + c * 256 + qoff;
#pragma unroll
      for (int kc = 0; kc < 8; ++kc) {
        bf16x8 av = *(const bf16x8*)&fb[arow + kc * 32];
        bf16x8 bv = *(const bf16x8*)(qp + kc * 32);
        if (kc & 1) ap1 = MFMA(av, bv, ap1, 0, 0, 0);
        else        ap0 = MFMA(av, bv, ap0, 0, 0, 0);
      }
    }
    if (l < 32) {
#pragma unroll
      for (int r = 0; r < 4; ++r) {
        float v = ap0[r] + ap1[r];
        x_s[((l >> 4) * 4 + r) * 200 + 128 + d0 + m16] = f2b(v);
      }
    }
  }
  __syncthreads();

  // ---------------- phase 3: MLP (B-frags from L2-resident ws) ----------------
  // layer 0: 192 -> 512, 8 n-tiles per wave
  {
    int ar = (m16 & 7) * 200 + qoff;
    bf16x8 xa[6];
#pragma unroll
    for (int kc = 0; kc < 6; ++kc) xa[kc] = *(const bf16x8*)&x_s[ar + kc * 32];
    for (int j = 0; j < 8; ++j) {
      int n0 = (w * 8 + j) * 16;
      const unsigned short* wp = w0t + (size_t)(n0 + m16) * 192 + qoff;
      f32x4 ha = {0.f, 0.f, 0.f, 0.f}, hb = {0.f, 0.f, 0.f, 0.f};
#pragma unroll
      for (int kc = 0; kc < 6; ++kc) {
        bf16x8 bv = *(const bf16x8*)(wp + kc * 32);
        if (kc & 1) hb = MFMA(xa[kc], bv, hb, 0, 0, 0);
        else        ha = MFMA(xa[kc], bv, ha, 0, 0, 0);
      }
      if (l < 32) {
        int n = n0 + m16;
        float sc = g0p[n] * rsqrtf(v0p[n] + BN_EPS);
        float sh = be0p[n] + (b0p[n] - m0p[n]) * sc;
#pragma unroll
        for (int r = 0; r < 4; ++r) {
          float v = fmaxf((ha[r] + hb[r]) * sc + sh, 0.f);
          h0_s[((l >> 4) * 4 + r) * 520 + n] = f2b(v);
        }
      }
    }
  }
  __syncthreads();

  // layer 1: 512 -> 256, 4 n-tiles per wave
  for (int j = 0; j < 4; ++j) {
    int n0 = (w * 4 + j) * 16;
    const unsigned short* wp = w1t + (size_t)(n0 + m16) * 512 + qoff;
    int ar = (m16 & 7) * 520 + qoff;
    f32x4 ha = {0.f, 0.f, 0.f, 0.f}, hb = {0.f, 0.f, 0.f, 0.f};
#pragma unroll
    for (int kc = 0; kc < 16; ++kc) {
      bf16x8 av = *(const bf16x8*)&h0_s[ar + kc * 32];
      bf16x8 bv = *(const bf16x8*)(wp + kc * 32);
      if (kc & 1) hb = MFMA(av, bv, hb, 0, 0, 0);
      else        ha = MFMA(av, bv, ha, 0, 0, 0);
    }
    if (l < 32) {
      int n = n0 + m16;
      float sc = g1p[n] * rsqrtf(v1p[n] + BN_EPS);
      float sh = be1p[n] + (b1p[n] - m1p[n]) * sc;
#pragma unroll
      for (int r = 0; r < 4; ++r) {
        float v = fmaxf((ha[r] + hb[r]) * sc + sh, 0.f);
        h1_s[((l >> 4) * 4 + r) * 264 + n] = f2b(v);
      }
    }
  }
  __syncthreads();

  // layer 2: 256 -> 128, 2 n-tiles per wave
  for (int j = 0; j < 2; ++j) {
    int n0 = (w * 2 + j) * 16;
    const unsigned short* wp = w2t + (size_t)(n0 + m16) * 256 + qoff;
    int ar = (m16 & 7) * 264 + qoff;
    f32x4 ha = {0.f, 0.f, 0.f, 0.f}, hb = {0.f, 0.f, 0.f, 0.f};
#pragma unroll
    for (int kc = 0; kc < 8; ++kc) {
      bf16x8 av = *(const bf16x8*)&h1_s[ar + kc * 32];
      bf16x8 bv = *(const bf16x8*)(wp + kc * 32);
      if (kc & 1) hb = MFMA(av, bv, hb, 0, 0, 0);
      else        ha = MFMA(av, bv, ha, 0, 0, 0);
    }
    if (l < 32) {
      int n = n0 + m16;
      float sc = g2p[n] * rsqrtf(v2p[n] + BN_EPS);
      float sh = be2p[n] + (b2p[n] - m2p[n]) * sc;
#pragma unroll
      for (int r = 0; r < 4; ++r) {
        float v = fmaxf((ha[r] + hb[r]) * sc + sh, 0.f);
        h2_s[((l >> 4) * 4 + r) * 136 + n] = f2b(v);
      }
    }
  }
  __syncthreads();

  // output: sigmoid(h2 @ Wout + bout), 8 rows
  if (t < 64) {
    int bb = t >> 3, seg = t & 7;
    float a = 0.f;
#pragma unroll
    for (int j = 0; j < 16; ++j) {
      int k = seg * 16 + j;
      a += bs2f(h2_s[bb * 136 + k]) * Wout[k];
    }
    a += __shfl_xor(a, 4); a += __shfl_xor(a, 2); a += __shfl_xor(a, 1);
    if (seg == 0) out[b0 + bb] = 1.f / (1.f + expf(-(a + boutp[0])));
  }
}

// ===========================================================================
extern "C" void kernel_launch(void* const* d_in, const int* in_sizes, int n_in,
                              void* d_out, int out_size, void* d_ws, size_t ws_size,
                              hipStream_t stream)
{
  (void)in_sizes; (void)n_in; (void)out_size; (void)ws_size;
  unsigned short* ws = (unsigned short*)d_ws;

  prep<<<292, 256, 0, stream>>>(
      (const float*)d_in[3], (const float*)d_in[5], (const float*)d_in[6],
      (const float*)d_in[12], (const float*)d_in[18], ws);

  pnn_main<<<B / ROWS, 256, 0, stream>>>(
      (const float*)d_in[0], (const int*)d_in[1], (const float*)d_in[2],
      (const float*)d_in[4], ws,
      (const float*)d_in[7],  (const float*)d_in[8],  (const float*)d_in[9],
      (const float*)d_in[10], (const float*)d_in[11],
      (const float*)d_in[13], (const float*)d_in[14], (const float*)d_in[15],
      (const float*)d_in[16], (const float*)d_in[17],
      (const float*)d_in[19], (const float*)d_in[20], (const float*)d_in[21],
      (const float*)d_in[22], (const float*)d_in[23],
      (const float*)d_in[24], (const float*)d_in[25],
      (float*)d_out);
}